// Round 1
// baseline (109.611 us; speedup 1.0000x reference)
//
#include <hip/hip_runtime.h>

// RelativeMultiHeadSelfAttention: B=16, S=1024, C=256, H=8 heads, D=32 head_dim
// Pipeline: prep (f32->bf16 casts + bias gather) -> QKV GEMM (bf16 MFMA) ->
//           fused attention (flash-style, no-max softmax) -> merge GEMM (f32 out)

typedef __attribute__((ext_vector_type(8))) short bf16x8;
typedef __attribute__((ext_vector_type(4))) float f32x4;

#define INV_LN2 1.44269504088896340736f

__device__ __forceinline__ unsigned short f2bf(float f) {
  union { float f; unsigned u; } v; v.f = f;
  unsigned r = v.u + 0x7fffu + ((v.u >> 16) & 1u);   // RNE
  return (unsigned short)(r >> 16);
}
__device__ __forceinline__ float bf2f(unsigned short h) {
  union { unsigned u; float f; } v; v.u = ((unsigned)h) << 16;
  return v.f;
}

// ---------------- prep: casts + bias gather ----------------
// units of 4 elements: x (1048576), w_qkv (49152), w_merge (16384), bias (262144)
__global__ __launch_bounds__(256) void prep_kernel(
    const float* __restrict__ x, const float* __restrict__ wq,
    const float* __restrict__ wm, const float* __restrict__ tab,
    const int* __restrict__ idx,
    unsigned short* __restrict__ xb, unsigned short* __restrict__ wqb,
    unsigned short* __restrict__ wmb, unsigned short* __restrict__ biasb) {
  const long NX = 1048576, NW1 = 49152, NW2 = 16384, NB = 262144;
  long u = (long)blockIdx.x * 256 + threadIdx.x;
  if (u < NX) {
    float4 v = ((const float4*)x)[u];
    ushort4 o; o.x = f2bf(v.x); o.y = f2bf(v.y); o.z = f2bf(v.z); o.w = f2bf(v.w);
    ((ushort4*)xb)[u] = o;
  } else if (u < NX + NW1) {
    long t = u - NX;
    float4 v = ((const float4*)wq)[t];
    ushort4 o; o.x = f2bf(v.x); o.y = f2bf(v.y); o.z = f2bf(v.z); o.w = f2bf(v.w);
    ((ushort4*)wqb)[t] = o;
  } else if (u < NX + NW1 + NW2) {
    long t = u - NX - NW1;
    float4 v = ((const float4*)wm)[t];
    ushort4 o; o.x = f2bf(v.x); o.y = f2bf(v.y); o.z = f2bf(v.z); o.w = f2bf(v.w);
    ((ushort4*)wmb)[t] = o;
  } else if (u < NX + NW1 + NW2 + NB) {
    long t = (u - NX - NW1 - NW2) * 4;
    int4 iv = ((const int4*)idx)[(u - NX - NW1 - NW2)];
    ushort4 o;
    o.x = f2bf(tab[(long)iv.x * 8] * INV_LN2);
    o.y = f2bf(tab[(long)iv.y * 8] * INV_LN2);
    o.z = f2bf(tab[(long)iv.z * 8] * INV_LN2);
    o.w = f2bf(tab[(long)iv.w * 8] * INV_LN2);
    ((ushort4*)biasb)[t / 4] = o;
  }
}

// ---------------- GEMM (shared for QKV and merge) ----------------
// C[m,n] = sum_k A[m,k]*Bw[n,k] (+ bias[n]); M tiles of 128 (grid.y), N tiles of 128 (grid.x)
// MODE 0: qkv -> scatter to q/k/v [bh][s][32] bf16, q scaled by 1/16
// MODE 1: merge -> f32 out[m*256+n]
template <int MODE>
__global__ __launch_bounds__(256) void gemm_k(
    const unsigned short* __restrict__ A, const unsigned short* __restrict__ Bw,
    const float* __restrict__ bias,
    unsigned short* __restrict__ q_ws, unsigned short* __restrict__ k_ws,
    unsigned short* __restrict__ v_ws, float* __restrict__ out) {
  __shared__ unsigned short As[128 * 32];
  __shared__ unsigned short Bs[128 * 32];
  const int tid = threadIdx.x;
  const int lane = tid & 63, wid = tid >> 6;
  const int wm = wid >> 1, wn = wid & 1;
  const int li = lane & 15, g = lane >> 4;
  const int m0 = blockIdx.y * 128;
  const int n0 = blockIdx.x * 128;
  f32x4 acc[4][4] = {};
  const int srow = tid >> 2, sg = tid & 3;
  const unsigned short* Ag = A + (long)(m0 + srow) * 256 + sg * 8;
  const unsigned short* Bg = Bw + (long)(n0 + srow) * 256 + sg * 8;

  for (int kt = 0; kt < 8; ++kt) {
    const int k0 = kt * 32;
    bf16x8 a0 = *(const bf16x8*)(Ag + k0);
    bf16x8 a1 = *(const bf16x8*)(Ag + 64 * 256 + k0);
    bf16x8 b0 = *(const bf16x8*)(Bg + k0);
    bf16x8 b1 = *(const bf16x8*)(Bg + 64 * 256 + k0);
    __syncthreads();
    ((bf16x8*)As)[tid] = a0;
    ((bf16x8*)As)[256 + tid] = a1;
    ((bf16x8*)Bs)[tid] = b0;
    ((bf16x8*)Bs)[256 + tid] = b1;
    __syncthreads();
    bf16x8 af[4], bfr[4];
#pragma unroll
    for (int mi = 0; mi < 4; mi++)
      af[mi] = *(const bf16x8*)(As + (wm * 64 + mi * 16 + li) * 32 + g * 8);
#pragma unroll
    for (int ni = 0; ni < 4; ni++)
      bfr[ni] = *(const bf16x8*)(Bs + (wn * 64 + ni * 16 + li) * 32 + g * 8);
#pragma unroll
    for (int mi = 0; mi < 4; mi++)
#pragma unroll
      for (int ni = 0; ni < 4; ni++)
        acc[mi][ni] = __builtin_amdgcn_mfma_f32_16x16x32_bf16(af[mi], bfr[ni], acc[mi][ni], 0, 0, 0);
  }

  if (MODE == 0) {
    const int sec = n0 >> 8;  // tile never crosses q/k/v section boundaries
    unsigned short* dst = (sec == 0) ? q_ws : ((sec == 1) ? k_ws : v_ws);
#pragma unroll
    for (int mi = 0; mi < 4; mi++)
#pragma unroll
      for (int ni = 0; ni < 4; ni++)
#pragma unroll
        for (int i = 0; i < 4; i++) {
          int m = m0 + wm * 64 + mi * 16 + g * 4 + i;
          int n = n0 + wn * 64 + ni * 16 + li;
          float val = acc[mi][ni][i] + bias[n];
          if (sec == 0) val *= 0.0625f;  // fold SCALE=1/16 into q (exact)
          int h = (n >> 5) & 7, d = n & 31;
          int b = m >> 10, s = m & 1023;
          dst[((long)(b * 8 + h) * 1024 + s) * 32 + d] = f2bf(val);
        }
  } else {
#pragma unroll
    for (int mi = 0; mi < 4; mi++)
#pragma unroll
      for (int ni = 0; ni < 4; ni++)
#pragma unroll
        for (int i = 0; i < 4; i++) {
          int m = m0 + wm * 64 + mi * 16 + g * 4 + i;
          int n = n0 + wn * 64 + ni * 16 + li;
          out[(long)m * 256 + n] = acc[mi][ni][i] + bias[n];
        }
  }
}

// ---------------- fused attention ----------------
// grid (16 q-tiles, 128 bh); 4 waves/WG, each wave owns 16 q rows.
// No max-subtraction softmax (logits are tiny; math identical): p=exp2(s*inv_ln2 + biasL2),
// O += P@V unnormalized, divide by per-row sum at the end.
__global__ __launch_bounds__(256) void attn_kernel(
    const unsigned short* __restrict__ q_ws, const unsigned short* __restrict__ k_ws,
    const unsigned short* __restrict__ v_ws, const unsigned short* __restrict__ biasb,
    unsigned short* __restrict__ attno) {
  __shared__ unsigned short Ks[64 * 32];      // [tok][d] linear
  __shared__ unsigned short Vt[32 * 64];      // [d][tok], XOR-swizzled
  __shared__ unsigned short Ps[4][16 * 72];   // per-wave P [16 q][72 toks padded]
  const int tid = threadIdx.x;
  const int lane = tid & 63, wid = tid >> 6;
  const int li = lane & 15, g = lane >> 4;
  const int bh = blockIdx.y;   // b*8+h
  const int q0 = blockIdx.x * 64 + wid * 16;
  const unsigned short* qb = q_ws + (long)bh * 1024 * 32;
  const unsigned short* kb = k_ws + (long)bh * 1024 * 32;
  const unsigned short* vb = v_ws + (long)bh * 1024 * 32;

  // Q fragment held in registers: A[m=li (q row)][k=g*8.. (head dim)]
  bf16x8 qf = *(const bf16x8*)(qb + (q0 + li) * 32 + g * 8);

  f32x4 o0 = {}, o1 = {};
  float lsum[4] = {0.f, 0.f, 0.f, 0.f};
  const int vtok = tid >> 2, vd0 = (tid & 3) * 8;
  const int vswz = (tid & 3) << 4;

  for (int kv0 = 0; kv0 < 1024; kv0 += 64) {
    bf16x8 kv8 = *(const bf16x8*)(kb + (kv0 + (tid >> 2)) * 32 + (tid & 3) * 8);
    bf16x8 vv8 = *(const bf16x8*)(vb + (kv0 + vtok) * 32 + vd0);
    __syncthreads();  // previous iteration's reads complete
    ((bf16x8*)Ks)[tid] = kv8;
#pragma unroll
    for (int j = 0; j < 8; j++) {
      int byteoff = (vd0 + j) * 128 + ((vtok * 2) ^ vswz);
      *(unsigned short*)((char*)Vt + byteoff) = (unsigned short)(unsigned)(unsigned short)vv8[j];
    }
    __syncthreads();

    // QK^T: s[c] = [16 q x 16 tok], full K=32 head dim in one MFMA
    f32x4 sc[4];
#pragma unroll
    for (int c = 0; c < 4; c++) {
      bf16x8 kf = *(const bf16x8*)(Ks + (c * 16 + li) * 32 + g * 8);
      f32x4 z = {};
      sc[c] = __builtin_amdgcn_mfma_f32_16x16x32_bf16(qf, kf, z, 0, 0, 0);
    }

    // softmax numerator + write P to LDS (A-frag layout for PV)
#pragma unroll
    for (int c = 0; c < 4; c++)
#pragma unroll
      for (int i = 0; i < 4; i++) {
        int qrow = g * 4 + i;
        float bl2 = bf2f(biasb[(long)(q0 + qrow) * 1024 + kv0 + c * 16 + li]);
        float p = exp2f(fmaf(sc[c][i], INV_LN2, bl2));
        lsum[i] += p;
        Ps[wid][qrow * 72 + c * 16 + li] = f2bf(p);
      }

    // PV: O[16 q x 32 d] over this 64-token tile
#pragma unroll
    for (int c2 = 0; c2 < 2; c2++) {
      bf16x8 pa = *(const bf16x8*)(&Ps[wid][li * 72 + c2 * 32 + g * 8]);
#pragma unroll
      for (int dblk = 0; dblk < 2; dblk++) {
        int d = li + dblk * 16;
        int byteoff = d * 128 + ((c2 * 64 + g * 16) ^ (((d >> 3) & 3) << 4));
        bf16x8 vf = *(const bf16x8*)((char*)Vt + byteoff);
        if (dblk == 0)
          o0 = __builtin_amdgcn_mfma_f32_16x16x32_bf16(pa, vf, o0, 0, 0, 0);
        else
          o1 = __builtin_amdgcn_mfma_f32_16x16x32_bf16(pa, vf, o1, 0, 0, 0);
      }
    }
  }

  // reduce row sums across the 16-lane token dim
#pragma unroll
  for (int i = 0; i < 4; i++) {
    float v = lsum[i];
    v += __shfl_xor(v, 1, 64);
    v += __shfl_xor(v, 2, 64);
    v += __shfl_xor(v, 4, 64);
    v += __shfl_xor(v, 8, 64);
    lsum[i] = v;
  }
  const int b = bh >> 3, h = bh & 7;
#pragma unroll
  for (int i = 0; i < 4; i++) {
    int srow = q0 + g * 4 + i;
    float inv = 1.0f / lsum[i];
    long base = ((long)(b * 1024 + srow)) * 256 + h * 32;
    attno[base + li] = f2bf(o0[i] * inv);
    attno[base + 16 + li] = f2bf(o1[i] * inv);
  }
}

// ---------------- launch ----------------
extern "C" void kernel_launch(void* const* d_in, const int* in_sizes, int n_in,
                              void* d_out, int out_size, void* d_ws, size_t ws_size,
                              hipStream_t stream) {
  const float* x      = (const float*)d_in[0];
  const float* wqkv   = (const float*)d_in[1];
  const float* bqkv   = (const float*)d_in[2];
  const float* wmerge = (const float*)d_in[3];
  const float* bmerge = (const float*)d_in[4];
  const float* rtab   = (const float*)d_in[5];
  const int*   ridx   = (const int*)d_in[6];
  float* out = (float*)d_out;

  char* ws = (char*)d_ws;
  unsigned short* xb    = (unsigned short*)(ws);                    //  8 MB
  unsigned short* wqb   = (unsigned short*)(ws + 8388608);          // 384 KB
  unsigned short* wmb   = (unsigned short*)(ws + 8781824);          // 128 KB
  unsigned short* biasb = (unsigned short*)(ws + 8912896);          //  2 MB
  unsigned short* q_ws  = (unsigned short*)(ws + 11010048);         //  8 MB
  unsigned short* k_ws  = (unsigned short*)(ws + 19398656);         //  8 MB
  unsigned short* v_ws  = (unsigned short*)(ws + 27787264);         //  8 MB
  unsigned short* attno = (unsigned short*)(ws + 36175872);         //  8 MB

  prep_kernel<<<5376, 256, 0, stream>>>(x, wqkv, wmerge, rtab, ridx, xb, wqb, wmb, biasb);
  gemm_k<0><<<dim3(6, 128), 256, 0, stream>>>(xb, wqb, bqkv, q_ws, k_ws, v_ws, nullptr);
  attn_kernel<<<dim3(16, 128), 256, 0, stream>>>(q_ws, k_ws, v_ws, biasb, attno);
  gemm_k<1><<<dim3(2, 128), 256, 0, stream>>>(attno, wmb, bmerge, nullptr, nullptr, nullptr, out);
}